// Round 16
// baseline (429.984 us; speedup 1.0000x reference)
//
#include <hip/hip_runtime.h>
#include <hip/hip_bf16.h>

typedef unsigned short u16;
typedef unsigned int   u32;
typedef u16   u16x8 __attribute__((ext_vector_type(8)));
typedef u16   u16x4 __attribute__((ext_vector_type(4)));
typedef __bf16 bf16x8 __attribute__((ext_vector_type(8)));
typedef float f32x4 __attribute__((ext_vector_type(4)));

__device__ __forceinline__ u16 f2bf(float f) {
    u32 u = __float_as_uint(f);
    u = u + 0x7FFFu + ((u >> 16) & 1u);   // RTNE (inputs are finite)
    return (u16)(u >> 16);
}
__device__ __forceinline__ float bf2f(u16 b) {
    return __uint_as_float((u32)b << 16);
}

__device__ __forceinline__ void gload16(const u16* g, u16* l) {
    __builtin_amdgcn_global_load_lds(
        (const __attribute__((address_space(1))) void*)g,
        (__attribute__((address_space(3))) void*)l,
        16, 0, 0);
}

#define WAITV(N) asm volatile("s_waitcnt vmcnt(" #N ")" ::: "memory")
#define SCHEDB() __builtin_amdgcn_sched_barrier(0)
#define BAR()    __builtin_amdgcn_s_barrier()

// ----------------------------------------------------- fused converts -------
// blocks [0,4096): X fp32 -> bf16 (8 elems/thread).
// blocks [4096,9216): 5 weights, 32x32 transpose tiles -> WT bf16.
__global__ __launch_bounds__(256)
void cvt_all(const float* __restrict__ X, u16* __restrict__ Xb,
             const float* __restrict__ w0, const float* __restrict__ w1,
             const float* __restrict__ w2, const float* __restrict__ w3,
             const float* __restrict__ w4, u16* __restrict__ wt) {
    const int bx  = blockIdx.x;
    const int tid = threadIdx.x;
    if (bx < 4096) {
        const long i = (long)(bx * 256 + tid) * 8;
        float4 a = *(const float4*)(X + i);
        float4 b = *(const float4*)(X + i + 4);
        u16x8 r;
        r[0] = f2bf(a.x); r[1] = f2bf(a.y); r[2] = f2bf(a.z); r[3] = f2bf(a.w);
        r[4] = f2bf(b.x); r[5] = f2bf(b.y); r[6] = f2bf(b.z); r[7] = f2bf(b.w);
        *(u16x8*)(Xb + i) = r;
        return;
    }
    const int wb  = bx - 4096;
    const int wz  = wb >> 10;
    const int rem = wb & 1023;
    const float* srcs[5] = {w0, w1, w2, w3, w4};
    const float* W = srcs[wz];
    u16* WT = wt + (long)wz * 1048576;
    __shared__ float t[32][33];
    const int tx = tid & 31, ty = tid >> 5;
    const int n0 = (rem & 31) * 32, k0 = (rem >> 5) * 32;
    #pragma unroll
    for (int r = 0; r < 4; ++r)
        t[ty + 8 * r][tx] = W[(long)(k0 + ty + 8 * r) * 1024 + n0 + tx];
    __syncthreads();
    #pragma unroll
    for (int r = 0; r < 4; ++r)
        WT[(long)(n0 + ty + 8 * r) * 1024 + k0 + tx] = f2bf(t[tx][ty + 8 * r]);
}

enum { EPI_QKV = 0, EPI_SCORES = 1, EPI_ADDX_BF16 = 3,
       EPI_BIAS_RELU_BF16 = 4, EPI_BIAS_ADDX_F32 = 5 };

// -------------------------------------- GEMM 256x128, BK=32, 3-slot ---------
// R13-proven structure (conflicts 0). Now also used for scores (EPI_SCORES:
// bf16 raw scaled scores into split Sb via Cout/CoutK).
#define BM3 256
#define BN3 128
#define BK3 32
#define S3_A (BM3 * BK3)
#define S3_B (BN3 * BK3)
#define S3SZ (S3_A + S3_B)

template <int EPI>
__global__ __launch_bounds__(512, 2)
void gemm_bt32(const u16* __restrict__ A, const u16* __restrict__ Bt,
               void* __restrict__ Cout, void* __restrict__ CoutK,
               void* __restrict__ CoutV,
               const int M, const int N, const int K,
               const long sA, const long sB,
               const float scale) {
    const int GX = gridDim.x, GY = gridDim.y;
    const int p  = blockIdx.x + GX * (blockIdx.y + GY * blockIdx.z);
    const int slab = (p & 7) + 8 * (p / (8 * GY));
    const int vy   = (p >> 3) % GY;
    const int vx   = slab % GX;
    const int bz   = slab / GX;

    const u16* Ab = A + (long)bz * sA;
    const u16* Bb = Bt + (long)bz * sB;

    const int tid  = threadIdx.x;
    const int lane = tid & 63;
    const int w    = tid >> 6;
    const int wrg  = (w >> 1) * 64;
    const int wcg  = (w & 1) * 64;
    const int m0   = vx * BM3;
    const int n0   = vy * BN3;

    __shared__ __align__(16) u16 LDS[3 * S3SZ];   // 72 KiB

    f32x4 acc[4][4] = {};

    const long Kl = K;
    const int schunk = ((lane & 3) ^ ((lane >> 3) & 3)) * 8;
    const u16* Ag = Ab + (long)(m0 + w * 32 + (lane >> 2)) * Kl + schunk;
    const u16* Bg = Bb + (long)(n0 + w * 16 + (lane >> 2)) * Kl + schunk;

    const int rbase = lane & 15;
    const int koff  = ((lane >> 4) ^ ((rbase >> 1) & 3)) * 8;

    const int dAoff = (w * 32) * BK3;
    const int dBoff = S3_A + (w * 16) * BK3;

    #define LDA3(mi) (*(const bf16x8*)(Asl + (wrg + (mi) * 16 + rbase) * BK3 + koff))
    #define LDB3(ni) (*(const bf16x8*)(Bsl + (wcg + (ni) * 16 + rbase) * BK3 + koff))
    #define STAGE3(KT, SLOT) do {                                  \
        u16* a_ = &LDS[(SLOT) * S3SZ + dAoff];                     \
        u16* b_ = &LDS[(SLOT) * S3SZ + dBoff];                     \
        gload16(Ag + (KT), a_);                                    \
        gload16(Ag + (KT) + 16 * Kl, a_ + 16 * BK3);               \
        gload16(Bg + (KT), b_);                                    \
    } while (0)

    const int nt = K / BK3;
    STAGE3(0, 0);
    STAGE3(BK3, 1);
    WAITV(3);
    BAR();

    int s = 0;
    for (int t = 0; t < nt; ++t) {
        const u16* Asl = &LDS[s * S3SZ];
        const u16* Bsl = &LDS[s * S3SZ + S3_A];
        const int s2 = (s + 2 >= 3) ? s - 1 : s + 2;
        const bool st = (t + 2 < nt);

        if (st) STAGE3((long)(t + 2) * BK3, s2);

        bf16x8 af[4], bf[4];
        #pragma unroll
        for (int mi = 0; mi < 4; ++mi) af[mi] = LDA3(mi);
        #pragma unroll
        for (int ni = 0; ni < 4; ++ni) bf[ni] = LDB3(ni);
        #pragma unroll
        for (int mi = 0; mi < 4; ++mi)
            #pragma unroll
            for (int ni = 0; ni < 4; ++ni)
                acc[mi][ni] = __builtin_amdgcn_mfma_f32_16x16x32_bf16(
                    af[mi], bf[ni], acc[mi][ni], 0, 0, 0);

        SCHEDB();
        if (st) { WAITV(3); } else { WAITV(0); }
        BAR();
        SCHEDB();
        s = (s == 2) ? 0 : s + 1;
    }
    #undef LDA3
    #undef LDB3
    #undef STAGE3

    const int colb = wcg + (lane & 15);
    const int rq   = (lane >> 4) * 4;
    #pragma unroll
    for (int mi = 0; mi < 4; ++mi) {
        #pragma unroll
        for (int ni = 0; ni < 4; ++ni) {
            f32x4 v = acc[mi][ni];
            const int gr0 = m0 + wrg + mi * 16 + rq;
            const int gc  = n0 + colb + ni * 16;
            if constexpr (EPI == EPI_QKV) {
                if (bz == 2) {
                    u16x4 p2;
                    p2[0] = f2bf(v[0]); p2[1] = f2bf(v[1]);
                    p2[2] = f2bf(v[2]); p2[3] = f2bf(v[3]);
                    u16* C = (u16*)CoutV;
                    const long off = ((long)(gr0 >> 11)) * 2097152 +
                                     (long)gc * 2048 + (gr0 & 2047);
                    *(u16x4*)(C + off) = p2;
                } else {
                    u16* C = (u16*)(bz == 0 ? Cout : CoutK);
                    #pragma unroll
                    for (int j = 0; j < 4; ++j)
                        C[(long)(gr0 + j) * N + gc] = f2bf(v[j]);
                }
            } else if constexpr (EPI == EPI_SCORES) {
                u16* Sb = (u16*)(bz < 2 ? Cout : CoutK) + (long)(bz & 1) * 4194304;
                #pragma unroll
                for (int j = 0; j < 4; ++j)
                    Sb[(long)(gr0 + j) * N + gc] = f2bf(v[j] * scale);
            }
        }
    }
}

// ------------------------- GEMM 256x128, BK=32, 2-slot, 3 blocks/CU (QKV) ---
// 2 x 24 KiB slots = 48 KiB -> 3 blocks/CU = 24 waves/CU. Depth-1 prefetch
// (gemm_big-proven scheme: stage t+1 into slot s^1 freed at t-1's barrier;
// WAITV(0)+BAR per tile). Bet: one clean 768-block round (768 = 256 CUs x 3)
// + deep TLP beats the 3-slot counted-wait at 2/CU (1.5 ragged rounds).
__global__ __launch_bounds__(512, 6)
void gemm_qkv3(const u16* __restrict__ A, const u16* __restrict__ Bt,
               void* __restrict__ Cout, void* __restrict__ CoutK,
               void* __restrict__ CoutV,
               const int M, const int N, const int K,
               const long sA, const long sB,
               const float scale) {
    const int GX = gridDim.x, GY = gridDim.y;
    const int p  = blockIdx.x + GX * (blockIdx.y + GY * blockIdx.z);
    const int slab = (p & 7) + 8 * (p / (8 * GY));
    const int vy   = (p >> 3) % GY;
    const int vx   = slab % GX;
    const int bz   = slab / GX;

    const u16* Ab = A + (long)bz * sA;
    const u16* Bb = Bt + (long)bz * sB;

    const int tid  = threadIdx.x;
    const int lane = tid & 63;
    const int w    = tid >> 6;
    const int wrg  = (w >> 1) * 64;
    const int wcg  = (w & 1) * 64;
    const int m0   = vx * BM3;
    const int n0   = vy * BN3;

    __shared__ __align__(16) u16 LDS[2 * S3SZ];   // 48 KiB

    f32x4 acc[4][4] = {};

    const long Kl = K;
    const int schunk = ((lane & 3) ^ ((lane >> 3) & 3)) * 8;
    const u16* Ag = Ab + (long)(m0 + w * 32 + (lane >> 2)) * Kl + schunk;
    const u16* Bg = Bb + (long)(n0 + w * 16 + (lane >> 2)) * Kl + schunk;

    const int rbase = lane & 15;
    const int koff  = ((lane >> 4) ^ ((rbase >> 1) & 3)) * 8;

    const int dAoff = (w * 32) * BK3;
    const int dBoff = S3_A + (w * 16) * BK3;

    #define LDA3(mi) (*(const bf16x8*)(Asl + (wrg + (mi) * 16 + rbase) * BK3 + koff))
    #define LDB3(ni) (*(const bf16x8*)(Bsl + (wcg + (ni) * 16 + rbase) * BK3 + koff))
    #define STAGE3(KT, SLOT) do {                                  \
        u16* a_ = &LDS[(SLOT) * S3SZ + dAoff];                     \
        u16* b_ = &LDS[(SLOT) * S3SZ + dBoff];                     \
        gload16(Ag + (KT), a_);                                    \
        gload16(Ag + (KT) + 16 * Kl, a_ + 16 * BK3);               \
        gload16(Bg + (KT), b_);                                    \
    } while (0)

    const int nt = K / BK3;
    STAGE3(0, 0);
    WAITV(0);
    BAR();

    for (int t = 0; t < nt; ++t) {
        const int s = t & 1;
        const u16* Asl = &LDS[s * S3SZ];
        const u16* Bsl = &LDS[s * S3SZ + S3_A];
        const bool st = (t + 1 < nt);

        if (st) STAGE3((long)(t + 1) * BK3, s ^ 1);

        bf16x8 af[4], bf[4];
        #pragma unroll
        for (int mi = 0; mi < 4; ++mi) af[mi] = LDA3(mi);
        #pragma unroll
        for (int ni = 0; ni < 4; ++ni) bf[ni] = LDB3(ni);
        #pragma unroll
        for (int mi = 0; mi < 4; ++mi)
            #pragma unroll
            for (int ni = 0; ni < 4; ++ni)
                acc[mi][ni] = __builtin_amdgcn_mfma_f32_16x16x32_bf16(
                    af[mi], bf[ni], acc[mi][ni], 0, 0, 0);

        SCHEDB();
        WAITV(0);
        BAR();
        SCHEDB();
    }
    #undef LDA3
    #undef LDB3
    #undef STAGE3

    const int colb = wcg + (lane & 15);
    const int rq   = (lane >> 4) * 4;
    #pragma unroll
    for (int mi = 0; mi < 4; ++mi) {
        #pragma unroll
        for (int ni = 0; ni < 4; ++ni) {
            f32x4 v = acc[mi][ni];
            const int gr0 = m0 + wrg + mi * 16 + rq;
            const int gc  = n0 + colb + ni * 16;
            if (bz == 2) {
                u16x4 p2;
                p2[0] = f2bf(v[0]); p2[1] = f2bf(v[1]);
                p2[2] = f2bf(v[2]); p2[3] = f2bf(v[3]);
                u16* C = (u16*)CoutV;
                const long off = ((long)(gr0 >> 11)) * 2097152 +
                                 (long)gc * 2048 + (gr0 & 2047);
                *(u16x4*)(C + off) = p2;
            } else {
                u16* C = (u16*)(bz == 0 ? Cout : CoutK);
                #pragma unroll
                for (int j = 0; j < 4; ++j)
                    C[(long)(gr0 + j) * N + gc] = f2bf(v[j]);
            }
        }
    }
}

// ------------------------------------------------- GEMM small (256x128, R10) -
#define BML 256
#define BNL 128
#define BKW 64
#define LSLOT_A (BML * BKW)
#define LSLOT_B (BNL * BKW)
#define LSLOTSZ (LSLOT_A + LSLOT_B)

template <int EPI>
__global__ __launch_bounds__(512, 1)
void gemm_bt(const u16* __restrict__ A, const u16* __restrict__ Bt,
             void* __restrict__ Cout,
             const float* __restrict__ bias, const float* __restrict__ Xres,
             const int M, const int N, const int K,
             const long sA, const long sB, const long sC, const long sX,
             const float scale) {
    const int GX = gridDim.x, GY = gridDim.y;
    const int p  = blockIdx.x + GX * (blockIdx.y + GY * blockIdx.z);
    const int slab = (p & 7) + 8 * (p / (8 * GY));
    const int vy   = (p >> 3) % GY;
    const int vx   = slab % GX;
    const int bz   = slab / GX;

    const u16* Ab = A + (long)bz * sA;
    const u16* Bb = Bt + (long)bz * sB;
    const float* Xr = Xres ? Xres + (long)bz * sX : nullptr;

    const int tid  = threadIdx.x;
    const int lane = tid & 63;
    const int w    = tid >> 6;
    const int wrg  = (w >> 1) * 64;
    const int wcg  = (w & 1) * 64;
    const int m0   = vx * BML;
    const int n0   = vy * BNL;

    __shared__ __align__(16) u16 LDS[3 * LSLOTSZ];   // 144 KiB

    f32x4 acc[4][4] = {};

    const long Kl = K;
    const int schunk = ((lane & 7) ^ (lane >> 3)) * 8;
    const u16* Ag = Ab + (long)(m0 + w * 32 + (lane >> 3)) * Kl + schunk;
    const u16* Bg = Bb + (long)(n0 + w * 16 + (lane >> 3)) * Kl + schunk;

    const int rbase = lane & 15;
    const int rx    = rbase & 7;
    const int q4    = lane >> 4;

    const int dAoff = (w * 32) * BKW;
    const int dBoff = LSLOT_A + (w * 16) * BKW;

    #define LDAL(mi, ks) (*(const bf16x8*)(Asl + (wrg + (mi) * 16 + rbase) * BKW \
                         + ((((ks) * 4 + q4) ^ rx)) * 8))
    #define LDBL(ni, ks) (*(const bf16x8*)(Bsl + (wcg + (ni) * 16 + rbase) * BKW \
                         + ((((ks) * 4 + q4) ^ rx)) * 8))

    const int nt = K / BKW;
    {
        u16* d0 = &LDS[0];
        gload16(Ag, d0 + dAoff);
        gload16(Ag + 8 * Kl,  d0 + dAoff + 512);
        gload16(Ag + 16 * Kl, d0 + dAoff + 1024);
        gload16(Ag + 24 * Kl, d0 + dAoff + 1536);
        gload16(Bg, d0 + dBoff);
        gload16(Bg + 8 * Kl,  d0 + dBoff + 512);
        u16* d1 = &LDS[LSLOTSZ];
        gload16(Ag + BKW, d1 + dAoff);
        gload16(Ag + BKW + 8 * Kl,  d1 + dAoff + 512);
        gload16(Ag + BKW + 16 * Kl, d1 + dAoff + 1024);
        gload16(Ag + BKW + 24 * Kl, d1 + dAoff + 1536);
        gload16(Bg + BKW, d1 + dBoff);
        gload16(Bg + BKW + 8 * Kl,  d1 + dBoff + 512);
    }
    WAITV(6);
    BAR();

    int s = 0;
    for (int t = 0; t < nt; ++t) {
        const u16* Asl = &LDS[s * LSLOTSZ];
        const u16* Bsl = &LDS[s * LSLOTSZ + LSLOT_A];
        const int s2 = (s + 2 >= 3) ? s - 1 : s + 2;
        u16* dA = &LDS[s2 * LSLOTSZ] + dAoff;
        u16* dB = &LDS[s2 * LSLOTSZ] + dBoff;
        const bool st = (t + 2 < nt);
        const long kt2 = (long)(t + 2) * BKW;

        if (st) {
            gload16(Ag + kt2, dA);
            gload16(Ag + kt2 + 8 * Kl,  dA + 512);
            gload16(Ag + kt2 + 16 * Kl, dA + 1024);
            gload16(Ag + kt2 + 24 * Kl, dA + 1536);
            gload16(Bg + kt2, dB);
            gload16(Bg + kt2 + 8 * Kl,  dB + 512);
        }

        bf16x8 af[4][2], bf[4][2];
        #pragma unroll
        for (int mi = 0; mi < 4; ++mi) {
            af[mi][0] = LDAL(mi, 0);
            af[mi][1] = LDAL(mi, 1);
        }
        #pragma unroll
        for (int ni = 0; ni < 4; ++ni) {
            bf[ni][0] = LDBL(ni, 0);
            bf[ni][1] = LDBL(ni, 1);
        }
        #pragma unroll
        for (int ks = 0; ks < 2; ++ks)
            #pragma unroll
            for (int mi = 0; mi < 4; ++mi)
                #pragma unroll
                for (int ni = 0; ni < 4; ++ni)
                    acc[mi][ni] = __builtin_amdgcn_mfma_f32_16x16x32_bf16(
                        af[mi][ks], bf[ni][ks], acc[mi][ni], 0, 0, 0);

        SCHEDB();
        if (st) { WAITV(6); } else { WAITV(0); }
        BAR();
        SCHEDB();
        s = (s == 2) ? 0 : s + 1;
    }
    #undef LDAL
    #undef LDBL

    const int colb = wcg + (lane & 15);
    const int rq   = (lane >> 4) * 4;
    #pragma unroll
    for (int mi = 0; mi < 4; ++mi) {
        #pragma unroll
        for (int ni = 0; ni < 4; ++ni) {
            f32x4 v = acc[mi][ni];
            const int gr0 = m0 + wrg + mi * 16 + rq;
            const int gc  = n0 + colb + ni * 16;
            #pragma unroll
            for (int j = 0; j < 4; ++j) {
                const long idx = (long)(gr0 + j) * N + gc;
                float val = v[j];
                if constexpr (EPI == EPI_ADDX_BF16) {
                    val += Xr[idx];
                    ((u16*)Cout + (long)bz * sC)[idx] = f2bf(val);
                } else if constexpr (EPI == EPI_BIAS_RELU_BF16) {
                    val = fmaxf(val + bias[gc], 0.0f);
                    ((u16*)Cout + (long)bz * sC)[idx] = f2bf(val);
                } else if constexpr (EPI == EPI_BIAS_ADDX_F32) {
                    ((float*)Cout + (long)bz * sC)[idx] =
                        val + bias[gc] + Xr[idx];
                }
            }
        }
    }
}

// ---------------------------------------------------------------- softmax ---
__global__ __launch_bounds__(256)
void softmax_rows(const u16* __restrict__ SbLo, const u16* __restrict__ SbHi,
                  float* __restrict__ attn, u16* __restrict__ P) {
    const int row  = blockIdx.x;
    const u16* srow = (row < 4096 ? SbLo + (long)row * 2048
                                  : SbHi + (long)(row - 4096) * 2048);
    const int tid  = threadIdx.x;
    const int lane = tid & 63;
    const int w    = tid >> 6;

    u16x8 raw = *(const u16x8*)(srow + tid * 8);
    float v[8];
    #pragma unroll
    for (int i = 0; i < 8; ++i) v[i] = bf2f(raw[i]);

    float m = fmaxf(fmaxf(fmaxf(v[0], v[1]), fmaxf(v[2], v[3])),
                    fmaxf(fmaxf(v[4], v[5]), fmaxf(v[6], v[7])));
    #pragma unroll
    for (int o = 32; o > 0; o >>= 1) m = fmaxf(m, __shfl_xor(m, o));
    __shared__ float redm[4];
    if (lane == 0) redm[w] = m;
    __syncthreads();
    m = fmaxf(fmaxf(redm[0], redm[1]), fmaxf(redm[2], redm[3]));

    float e[8];
    #pragma unroll
    for (int i = 0; i < 8; ++i) e[i] = __expf(v[i] - m);
    float s = ((e[0] + e[1]) + (e[2] + e[3])) + ((e[4] + e[5]) + (e[6] + e[7]));
    #pragma unroll
    for (int o = 32; o > 0; o >>= 1) s += __shfl_xor(s, o);
    __shared__ float reds[4];
    if (lane == 0) reds[w] = s;
    __syncthreads();
    s = (reds[0] + reds[1]) + (reds[2] + reds[3]);
    const float inv = 1.0f / s;

    float4 o0, o1;
    o0.x = e[0] * inv; o0.y = e[1] * inv; o0.z = e[2] * inv; o0.w = e[3] * inv;
    o1.x = e[4] * inv; o1.y = e[5] * inv; o1.z = e[6] * inv; o1.w = e[7] * inv;
    float* ap = attn + (long)row * 2048 + tid * 8;
    *(float4*)(ap)     = o0;
    *(float4*)(ap + 4) = o1;

    u16x8 pb;
    pb[0] = f2bf(o0.x); pb[1] = f2bf(o0.y); pb[2] = f2bf(o0.z); pb[3] = f2bf(o0.w);
    pb[4] = f2bf(o1.x); pb[5] = f2bf(o1.y); pb[6] = f2bf(o1.z); pb[7] = f2bf(o1.w);
    *(u16x8*)(P + (long)row * 2048 + tid * 8) = pb;
}

// ------------------------------------------------------------------ launch --
extern "C" void kernel_launch(void* const* d_in, const int* in_sizes, int n_in,
                              void* d_out, int out_size, void* d_ws, size_t ws_size,
                              hipStream_t stream) {
    const float* X  = (const float*)d_in[0];
    const float* Wq = (const float*)d_in[1];
    const float* Wk = (const float*)d_in[2];
    const float* Wv = (const float*)d_in[3];
    const float* W1 = (const float*)d_in[4];
    const float* b1 = (const float*)d_in[5];
    const float* W2 = (const float*)d_in[6];
    const float* b2 = (const float*)d_in[7];

    float* out  = (float*)d_out;                    // [4,2048,1024]
    float* attn = out + (size_t)8388608;            // [4,2048,2048]

    char* ws = (char*)d_ws;
    u16* Xb  = (u16*)(ws);                               // 16 MiB
    u16* Qb  = (u16*)(ws + (size_t)16 * 1024 * 1024);    // 16 MiB
    u16* Kb  = (u16*)(ws + (size_t)32 * 1024 * 1024);    // 16 MiB
    u16* VT  = (u16*)(ws + (size_t)48 * 1024 * 1024);    // 16 MiB  V^T [b][d][s]
    u16* H1b = (u16*)(ws + (size_t)64 * 1024 * 1024);    // 16 MiB
    u16* WTs = (u16*)(ws + (size_t)80 * 1024 * 1024);    // 10 MiB
    u16* W1T = WTs + (size_t)3 * 1048576;
    u16* W2T = WTs + (size_t)4 * 1048576;
    u16* SbLo = Xb;    // raw scores batches 0-1 (Xb dead after QKV)
    u16* SbHi = H1b;   // raw scores batches 2-3 (H1b dead until W1)
    u16* Pb  = Xb;     // P bf16 over Xb+Qb (Qb dead post-scores)
    u16* Hb  = Kb;     // alias over Kb (dead after scores GEMM)

    cvt_all<<<9216, 256, 0, stream>>>(X, Xb, Wq, Wk, Wv, W1, W2, WTs);

    // fused Q,K,V: 2-slot 48 KiB -> 3 blocks/CU (one clean 768-block round)
    gemm_qkv3<<<dim3(32, 8, 3), 512, 0, stream>>>(
        Xb, WTs, Qb, Kb, VT, 8192, 1024, 1024, 0, 1048576, 1.0f);

    // scores = Q @ K^T / 32 -> bf16 raw Sb (512 blocks -> 2/CU)
    gemm_bt32<EPI_SCORES><<<dim3(8, 16, 4), 512, 0, stream>>>(
        Qb, Kb, SbLo, SbHi, nullptr, 2048, 2048, 1024,
        2048L * 1024, 2048L * 1024, 0.03125f);

    // softmax: bf16 Sb -> fp32 attn (output) + bf16 P
    softmax_rows<<<8192, 256, 0, stream>>>(SbLo, SbHi, attn, Pb);

    // attn_out = P @ V, + X residual -> Hb (bf16)
    gemm_bt<EPI_ADDX_BF16><<<dim3(8, 8, 4), 512, 0, stream>>>(
        Pb, VT, Hb, nullptr, X, 2048, 1024, 2048,
        2048L * 2048, 1024L * 2048, 2048L * 1024, 2048L * 1024, 1.0f);

    // h1 = relu(Hb @ W1 + b1)
    gemm_bt<EPI_BIAS_RELU_BF16><<<dim3(32, 8, 1), 512, 0, stream>>>(
        Hb, W1T, H1b, b1, nullptr, 8192, 1024, 1024, 0, 0, 0, 0, 1.0f);

    // out = h1 @ W2 + b2 + X
    gemm_bt<EPI_BIAS_ADDX_F32><<<dim3(32, 8, 1), 512, 0, stream>>>(
        H1b, W2T, out, b2, X, 8192, 1024, 1024, 0, 0, 0, 0, 1.0f);
}

// Round 17
// 228.911 us; speedup vs baseline: 1.8784x; 1.8784x over previous
//
#include <hip/hip_runtime.h>
#include <hip/hip_bf16.h>

typedef unsigned short u16;
typedef unsigned int   u32;
typedef u16   u16x8 __attribute__((ext_vector_type(8)));
typedef u16   u16x4 __attribute__((ext_vector_type(4)));
typedef __bf16 bf16x8 __attribute__((ext_vector_type(8)));
typedef float f32x4 __attribute__((ext_vector_type(4)));

__device__ __forceinline__ u16 f2bf(float f) {
    u32 u = __float_as_uint(f);
    u = u + 0x7FFFu + ((u >> 16) & 1u);   // RTNE (inputs are finite)
    return (u16)(u >> 16);
}
__device__ __forceinline__ float bf2f(u16 b) {
    return __uint_as_float((u32)b << 16);
}

__device__ __forceinline__ void gload16(const u16* g, u16* l) {
    __builtin_amdgcn_global_load_lds(
        (const __attribute__((address_space(1))) void*)g,
        (__attribute__((address_space(3))) void*)l,
        16, 0, 0);
}

#define WAITV(N) asm volatile("s_waitcnt vmcnt(" #N ")" ::: "memory")
#define SCHEDB() __builtin_amdgcn_sched_barrier(0)
#define BAR()    __builtin_amdgcn_s_barrier()

// ----------------------------------------------------- fused converts -------
// blocks [0,4096): X fp32 -> bf16 (8 elems/thread).
// blocks [4096,9216): 5 weights, 32x32 transpose tiles -> WT bf16.
__global__ __launch_bounds__(256)
void cvt_all(const float* __restrict__ X, u16* __restrict__ Xb,
             const float* __restrict__ w0, const float* __restrict__ w1,
             const float* __restrict__ w2, const float* __restrict__ w3,
             const float* __restrict__ w4, u16* __restrict__ wt) {
    const int bx  = blockIdx.x;
    const int tid = threadIdx.x;
    if (bx < 4096) {
        const long i = (long)(bx * 256 + tid) * 8;
        float4 a = *(const float4*)(X + i);
        float4 b = *(const float4*)(X + i + 4);
        u16x8 r;
        r[0] = f2bf(a.x); r[1] = f2bf(a.y); r[2] = f2bf(a.z); r[3] = f2bf(a.w);
        r[4] = f2bf(b.x); r[5] = f2bf(b.y); r[6] = f2bf(b.z); r[7] = f2bf(b.w);
        *(u16x8*)(Xb + i) = r;
        return;
    }
    const int wb  = bx - 4096;
    const int wz  = wb >> 10;
    const int rem = wb & 1023;
    const float* srcs[5] = {w0, w1, w2, w3, w4};
    const float* W = srcs[wz];
    u16* WT = wt + (long)wz * 1048576;
    __shared__ float t[32][33];
    const int tx = tid & 31, ty = tid >> 5;
    const int n0 = (rem & 31) * 32, k0 = (rem >> 5) * 32;
    #pragma unroll
    for (int r = 0; r < 4; ++r)
        t[ty + 8 * r][tx] = W[(long)(k0 + ty + 8 * r) * 1024 + n0 + tx];
    __syncthreads();
    #pragma unroll
    for (int r = 0; r < 4; ++r)
        WT[(long)(n0 + ty + 8 * r) * 1024 + k0 + tx] = f2bf(t[tx][ty + 8 * r]);
}

enum { EPI_QKV = 0, EPI_SCORES = 1, EPI_ADDX_BF16 = 3,
       EPI_BIAS_RELU_BF16 = 4, EPI_BIAS_ADDX_F32 = 5 };

// -------------------------------------- GEMM 256x128, BK=32, 2 blocks/CU ----
// R13-proven (QKV 61.3us, MfmaUtil 35%, conflicts 0, 52 VGPR no spill).
// EPI_QKV: bf16 Q/K + transposed V. EPI_SCORES: bf16 raw scaled scores into
// split Sb (bz<2 -> Cout[SbLo], else CoutK[SbHi]).
#define BM3 256
#define BN3 128
#define BK3 32
#define S3_A (BM3 * BK3)
#define S3_B (BN3 * BK3)
#define S3SZ (S3_A + S3_B)

template <int EPI>
__global__ __launch_bounds__(512, 2)
void gemm_bt32(const u16* __restrict__ A, const u16* __restrict__ Bt,
               void* __restrict__ Cout, void* __restrict__ CoutK,
               void* __restrict__ CoutV,
               const int M, const int N, const int K,
               const long sA, const long sB,
               const float scale) {
    const int GX = gridDim.x, GY = gridDim.y;
    const int p  = blockIdx.x + GX * (blockIdx.y + GY * blockIdx.z);
    const int slab = (p & 7) + 8 * (p / (8 * GY));
    const int vy   = (p >> 3) % GY;
    const int vx   = slab % GX;
    const int bz   = slab / GX;

    const u16* Ab = A + (long)bz * sA;
    const u16* Bb = Bt + (long)bz * sB;

    const int tid  = threadIdx.x;
    const int lane = tid & 63;
    const int w    = tid >> 6;
    const int wrg  = (w >> 1) * 64;
    const int wcg  = (w & 1) * 64;
    const int m0   = vx * BM3;
    const int n0   = vy * BN3;

    __shared__ __align__(16) u16 LDS[3 * S3SZ];   // 72 KiB

    f32x4 acc[4][4] = {};

    const long Kl = K;
    const int schunk = ((lane & 3) ^ ((lane >> 3) & 3)) * 8;
    const u16* Ag = Ab + (long)(m0 + w * 32 + (lane >> 2)) * Kl + schunk;
    const u16* Bg = Bb + (long)(n0 + w * 16 + (lane >> 2)) * Kl + schunk;

    const int rbase = lane & 15;
    const int koff  = ((lane >> 4) ^ ((rbase >> 1) & 3)) * 8;

    const int dAoff = (w * 32) * BK3;
    const int dBoff = S3_A + (w * 16) * BK3;

    #define LDA3(mi) (*(const bf16x8*)(Asl + (wrg + (mi) * 16 + rbase) * BK3 + koff))
    #define LDB3(ni) (*(const bf16x8*)(Bsl + (wcg + (ni) * 16 + rbase) * BK3 + koff))
    #define STAGE3(KT, SLOT) do {                                  \
        u16* a_ = &LDS[(SLOT) * S3SZ + dAoff];                     \
        u16* b_ = &LDS[(SLOT) * S3SZ + dBoff];                     \
        gload16(Ag + (KT), a_);                                    \
        gload16(Ag + (KT) + 16 * Kl, a_ + 16 * BK3);               \
        gload16(Bg + (KT), b_);                                    \
    } while (0)

    const int nt = K / BK3;
    STAGE3(0, 0);
    STAGE3(BK3, 1);
    WAITV(3);
    BAR();

    int s = 0;
    for (int t = 0; t < nt; ++t) {
        const u16* Asl = &LDS[s * S3SZ];
        const u16* Bsl = &LDS[s * S3SZ + S3_A];
        const int s2 = (s + 2 >= 3) ? s - 1 : s + 2;
        const bool st = (t + 2 < nt);

        if (st) STAGE3((long)(t + 2) * BK3, s2);

        bf16x8 af[4], bf[4];
        #pragma unroll
        for (int mi = 0; mi < 4; ++mi) af[mi] = LDA3(mi);
        #pragma unroll
        for (int ni = 0; ni < 4; ++ni) bf[ni] = LDB3(ni);
        #pragma unroll
        for (int mi = 0; mi < 4; ++mi)
            #pragma unroll
            for (int ni = 0; ni < 4; ++ni)
                acc[mi][ni] = __builtin_amdgcn_mfma_f32_16x16x32_bf16(
                    af[mi], bf[ni], acc[mi][ni], 0, 0, 0);

        SCHEDB();
        if (st) { WAITV(3); } else { WAITV(0); }
        BAR();
        SCHEDB();
        s = (s == 2) ? 0 : s + 1;
    }
    #undef LDA3
    #undef LDB3
    #undef STAGE3

    const int colb = wcg + (lane & 15);
    const int rq   = (lane >> 4) * 4;
    #pragma unroll
    for (int mi = 0; mi < 4; ++mi) {
        #pragma unroll
        for (int ni = 0; ni < 4; ++ni) {
            f32x4 v = acc[mi][ni];
            const int gr0 = m0 + wrg + mi * 16 + rq;
            const int gc  = n0 + colb + ni * 16;
            if constexpr (EPI == EPI_QKV) {
                if (bz == 2) {
                    u16x4 p2;
                    p2[0] = f2bf(v[0]); p2[1] = f2bf(v[1]);
                    p2[2] = f2bf(v[2]); p2[3] = f2bf(v[3]);
                    u16* C = (u16*)CoutV;
                    const long off = ((long)(gr0 >> 11)) * 2097152 +
                                     (long)gc * 2048 + (gr0 & 2047);
                    *(u16x4*)(C + off) = p2;
                } else {
                    u16* C = (u16*)(bz == 0 ? Cout : CoutK);
                    #pragma unroll
                    for (int j = 0; j < 4; ++j)
                        C[(long)(gr0 + j) * N + gc] = f2bf(v[j]);
                }
            } else if constexpr (EPI == EPI_SCORES) {
                u16* Sb = (u16*)(bz < 2 ? Cout : CoutK) + (long)(bz & 1) * 4194304;
                #pragma unroll
                for (int j = 0; j < 4; ++j)
                    Sb[(long)(gr0 + j) * N + gc] = f2bf(v[j] * scale);
            }
        }
    }
}

// ------------------------------------------------- GEMM small (256x128, R10) -
#define BML 256
#define BNL 128
#define BKW 64
#define LSLOT_A (BML * BKW)
#define LSLOT_B (BNL * BKW)
#define LSLOTSZ (LSLOT_A + LSLOT_B)

template <int EPI>
__global__ __launch_bounds__(512, 1)
void gemm_bt(const u16* __restrict__ A, const u16* __restrict__ Bt,
             void* __restrict__ Cout,
             const float* __restrict__ bias, const float* __restrict__ Xres,
             const int M, const int N, const int K,
             const long sA, const long sB, const long sC, const long sX,
             const float scale) {
    const int GX = gridDim.x, GY = gridDim.y;
    const int p  = blockIdx.x + GX * (blockIdx.y + GY * blockIdx.z);
    const int slab = (p & 7) + 8 * (p / (8 * GY));
    const int vy   = (p >> 3) % GY;
    const int vx   = slab % GX;
    const int bz   = slab / GX;

    const u16* Ab = A + (long)bz * sA;
    const u16* Bb = Bt + (long)bz * sB;
    const float* Xr = Xres ? Xres + (long)bz * sX : nullptr;

    const int tid  = threadIdx.x;
    const int lane = tid & 63;
    const int w    = tid >> 6;
    const int wrg  = (w >> 1) * 64;
    const int wcg  = (w & 1) * 64;
    const int m0   = vx * BML;
    const int n0   = vy * BNL;

    __shared__ __align__(16) u16 LDS[3 * LSLOTSZ];   // 144 KiB

    f32x4 acc[4][4] = {};

    const long Kl = K;
    const int schunk = ((lane & 7) ^ (lane >> 3)) * 8;
    const u16* Ag = Ab + (long)(m0 + w * 32 + (lane >> 3)) * Kl + schunk;
    const u16* Bg = Bb + (long)(n0 + w * 16 + (lane >> 3)) * Kl + schunk;

    const int rbase = lane & 15;
    const int rx    = rbase & 7;
    const int q4    = lane >> 4;

    const int dAoff = (w * 32) * BKW;
    const int dBoff = LSLOT_A + (w * 16) * BKW;

    #define LDAL(mi, ks) (*(const bf16x8*)(Asl + (wrg + (mi) * 16 + rbase) * BKW \
                         + ((((ks) * 4 + q4) ^ rx)) * 8))
    #define LDBL(ni, ks) (*(const bf16x8*)(Bsl + (wcg + (ni) * 16 + rbase) * BKW \
                         + ((((ks) * 4 + q4) ^ rx)) * 8))

    const int nt = K / BKW;
    {
        u16* d0 = &LDS[0];
        gload16(Ag, d0 + dAoff);
        gload16(Ag + 8 * Kl,  d0 + dAoff + 512);
        gload16(Ag + 16 * Kl, d0 + dAoff + 1024);
        gload16(Ag + 24 * Kl, d0 + dAoff + 1536);
        gload16(Bg, d0 + dBoff);
        gload16(Bg + 8 * Kl,  d0 + dBoff + 512);
        u16* d1 = &LDS[LSLOTSZ];
        gload16(Ag + BKW, d1 + dAoff);
        gload16(Ag + BKW + 8 * Kl,  d1 + dAoff + 512);
        gload16(Ag + BKW + 16 * Kl, d1 + dAoff + 1024);
        gload16(Ag + BKW + 24 * Kl, d1 + dAoff + 1536);
        gload16(Bg + BKW, d1 + dBoff);
        gload16(Bg + BKW + 8 * Kl,  d1 + dBoff + 512);
    }
    WAITV(6);
    BAR();

    int s = 0;
    for (int t = 0; t < nt; ++t) {
        const u16* Asl = &LDS[s * LSLOTSZ];
        const u16* Bsl = &LDS[s * LSLOTSZ + LSLOT_A];
        const int s2 = (s + 2 >= 3) ? s - 1 : s + 2;
        u16* dA = &LDS[s2 * LSLOTSZ] + dAoff;
        u16* dB = &LDS[s2 * LSLOTSZ] + dBoff;
        const bool st = (t + 2 < nt);
        const long kt2 = (long)(t + 2) * BKW;

        if (st) {
            gload16(Ag + kt2, dA);
            gload16(Ag + kt2 + 8 * Kl,  dA + 512);
            gload16(Ag + kt2 + 16 * Kl, dA + 1024);
            gload16(Ag + kt2 + 24 * Kl, dA + 1536);
            gload16(Bg + kt2, dB);
            gload16(Bg + kt2 + 8 * Kl,  dB + 512);
        }

        bf16x8 af[4][2], bf[4][2];
        #pragma unroll
        for (int mi = 0; mi < 4; ++mi) {
            af[mi][0] = LDAL(mi, 0);
            af[mi][1] = LDAL(mi, 1);
        }
        #pragma unroll
        for (int ni = 0; ni < 4; ++ni) {
            bf[ni][0] = LDBL(ni, 0);
            bf[ni][1] = LDBL(ni, 1);
        }
        #pragma unroll
        for (int ks = 0; ks < 2; ++ks)
            #pragma unroll
            for (int mi = 0; mi < 4; ++mi)
                #pragma unroll
                for (int ni = 0; ni < 4; ++ni)
                    acc[mi][ni] = __builtin_amdgcn_mfma_f32_16x16x32_bf16(
                        af[mi][ks], bf[ni][ks], acc[mi][ni], 0, 0, 0);

        SCHEDB();
        if (st) { WAITV(6); } else { WAITV(0); }
        BAR();
        SCHEDB();
        s = (s == 2) ? 0 : s + 1;
    }
    #undef LDAL
    #undef LDBL

    const int colb = wcg + (lane & 15);
    const int rq   = (lane >> 4) * 4;
    #pragma unroll
    for (int mi = 0; mi < 4; ++mi) {
        #pragma unroll
        for (int ni = 0; ni < 4; ++ni) {
            f32x4 v = acc[mi][ni];
            const int gr0 = m0 + wrg + mi * 16 + rq;
            const int gc  = n0 + colb + ni * 16;
            #pragma unroll
            for (int j = 0; j < 4; ++j) {
                const long idx = (long)(gr0 + j) * N + gc;
                float val = v[j];
                if constexpr (EPI == EPI_ADDX_BF16) {
                    val += Xr[idx];
                    ((u16*)Cout + (long)bz * sC)[idx] = f2bf(val);
                } else if constexpr (EPI == EPI_BIAS_RELU_BF16) {
                    val = fmaxf(val + bias[gc], 0.0f);
                    ((u16*)Cout + (long)bz * sC)[idx] = f2bf(val);
                } else if constexpr (EPI == EPI_BIAS_ADDX_F32) {
                    ((float*)Cout + (long)bz * sC)[idx] =
                        val + bias[gc] + Xr[idx];
                }
            }
        }
    }
}

// ---------------------------------------------------------------- softmax ---
__global__ __launch_bounds__(256)
void softmax_rows(const u16* __restrict__ SbLo, const u16* __restrict__ SbHi,
                  float* __restrict__ attn, u16* __restrict__ P) {
    const int row  = blockIdx.x;
    const u16* srow = (row < 4096 ? SbLo + (long)row * 2048
                                  : SbHi + (long)(row - 4096) * 2048);
    const int tid  = threadIdx.x;
    const int lane = tid & 63;
    const int w    = tid >> 6;

    u16x8 raw = *(const u16x8*)(srow + tid * 8);
    float v[8];
    #pragma unroll
    for (int i = 0; i < 8; ++i) v[i] = bf2f(raw[i]);

    float m = fmaxf(fmaxf(fmaxf(v[0], v[1]), fmaxf(v[2], v[3])),
                    fmaxf(fmaxf(v[4], v[5]), fmaxf(v[6], v[7])));
    #pragma unroll
    for (int o = 32; o > 0; o >>= 1) m = fmaxf(m, __shfl_xor(m, o));
    __shared__ float redm[4];
    if (lane == 0) redm[w] = m;
    __syncthreads();
    m = fmaxf(fmaxf(redm[0], redm[1]), fmaxf(redm[2], redm[3]));

    float e[8];
    #pragma unroll
    for (int i = 0; i < 8; ++i) e[i] = __expf(v[i] - m);
    float s = ((e[0] + e[1]) + (e[2] + e[3])) + ((e[4] + e[5]) + (e[6] + e[7]));
    #pragma unroll
    for (int o = 32; o > 0; o >>= 1) s += __shfl_xor(s, o);
    __shared__ float reds[4];
    if (lane == 0) reds[w] = s;
    __syncthreads();
    s = (reds[0] + reds[1]) + (reds[2] + reds[3]);
    const float inv = 1.0f / s;

    float4 o0, o1;
    o0.x = e[0] * inv; o0.y = e[1] * inv; o0.z = e[2] * inv; o0.w = e[3] * inv;
    o1.x = e[4] * inv; o1.y = e[5] * inv; o1.z = e[6] * inv; o1.w = e[7] * inv;
    float* ap = attn + (long)row * 2048 + tid * 8;
    *(float4*)(ap)     = o0;
    *(float4*)(ap + 4) = o1;

    u16x8 pb;
    pb[0] = f2bf(o0.x); pb[1] = f2bf(o0.y); pb[2] = f2bf(o0.z); pb[3] = f2bf(o0.w);
    pb[4] = f2bf(o1.x); pb[5] = f2bf(o1.y); pb[6] = f2bf(o1.z); pb[7] = f2bf(o1.w);
    *(u16x8*)(P + (long)row * 2048 + tid * 8) = pb;
}

// ------------------------------------------------------------------ launch --
extern "C" void kernel_launch(void* const* d_in, const int* in_sizes, int n_in,
                              void* d_out, int out_size, void* d_ws, size_t ws_size,
                              hipStream_t stream) {
    const float* X  = (const float*)d_in[0];
    const float* Wq = (const float*)d_in[1];
    const float* Wk = (const float*)d_in[2];
    const float* Wv = (const float*)d_in[3];
    const float* W1 = (const float*)d_in[4];
    const float* b1 = (const float*)d_in[5];
    const float* W2 = (const float*)d_in[6];
    const float* b2 = (const float*)d_in[7];

    float* out  = (float*)d_out;                    // [4,2048,1024]
    float* attn = out + (size_t)8388608;            // [4,2048,2048]

    char* ws = (char*)d_ws;
    u16* Xb  = (u16*)(ws);                               // 16 MiB
    u16* Qb  = (u16*)(ws + (size_t)16 * 1024 * 1024);    // 16 MiB
    u16* Kb  = (u16*)(ws + (size_t)32 * 1024 * 1024);    // 16 MiB
    u16* VT  = (u16*)(ws + (size_t)48 * 1024 * 1024);    // 16 MiB  V^T [b][d][s]
    u16* H1b = (u16*)(ws + (size_t)64 * 1024 * 1024);    // 16 MiB
    u16* WTs = (u16*)(ws + (size_t)80 * 1024 * 1024);    // 10 MiB
    u16* W1T = WTs + (size_t)3 * 1048576;
    u16* W2T = WTs + (size_t)4 * 1048576;
    u16* SbLo = Xb;    // raw scores batches 0-1 (Xb dead after QKV)
    u16* SbHi = H1b;   // raw scores batches 2-3 (H1b dead until W1)
    u16* Pb  = Xb;     // P bf16 over Xb+Qb (Qb dead post-scores)
    u16* Hb  = Kb;     // alias over Kb (dead after scores GEMM)

    cvt_all<<<9216, 256, 0, stream>>>(X, Xb, Wq, Wk, Wv, W1, W2, WTs);

    // fused Q,K,V: R13-proven gemm_bt32 (3-slot, 72 KiB, 2 blocks/CU)
    gemm_bt32<EPI_QKV><<<dim3(32, 8, 3), 512, 0, stream>>>(
        Xb, WTs, Qb, Kb, VT, 8192, 1024, 1024, 0, 1048576, 1.0f);

    // scores = Q @ K^T / 32 -> bf16 raw Sb (512 blocks -> 2/CU)
    gemm_bt32<EPI_SCORES><<<dim3(8, 16, 4), 512, 0, stream>>>(
        Qb, Kb, SbLo, SbHi, nullptr, 2048, 2048, 1024,
        2048L * 1024, 2048L * 1024, 0.03125f);

    // softmax: bf16 Sb -> fp32 attn (output) + bf16 P
    softmax_rows<<<8192, 256, 0, stream>>>(SbLo, SbHi, attn, Pb);

    // attn_out = P @ V, + X residual -> Hb (bf16)
    gemm_bt<EPI_ADDX_BF16><<<dim3(8, 8, 4), 512, 0, stream>>>(
        Pb, VT, Hb, nullptr, X, 2048, 1024, 2048,
        2048L * 2048, 1024L * 2048, 2048L * 1024, 2048L * 1024, 1.0f);

    // h1 = relu(Hb @ W1 + b1)
    gemm_bt<EPI_BIAS_RELU_BF16><<<dim3(32, 8, 1), 512, 0, stream>>>(
        Hb, W1T, H1b, b1, nullptr, 8192, 1024, 1024, 0, 0, 0, 0, 1.0f);

    // out = h1 @ W2 + b2 + X
    gemm_bt<EPI_BIAS_ADDX_F32><<<dim3(32, 8, 1), 512, 0, stream>>>(
        H1b, W2T, out, b2, X, 8192, 1024, 1024, 0, 0, 0, 0, 1.0f);
}

// Round 18
// 226.835 us; speedup vs baseline: 1.8956x; 1.0092x over previous
//
#include <hip/hip_runtime.h>
#include <hip/hip_bf16.h>

typedef unsigned short u16;
typedef unsigned int   u32;
typedef u16   u16x8 __attribute__((ext_vector_type(8)));
typedef u16   u16x4 __attribute__((ext_vector_type(4)));
typedef __bf16 bf16x8 __attribute__((ext_vector_type(8)));
typedef float f32x4 __attribute__((ext_vector_type(4)));

__device__ __forceinline__ u16 f2bf(float f) {
    u32 u = __float_as_uint(f);
    u = u + 0x7FFFu + ((u >> 16) & 1u);   // RTNE (inputs are finite)
    return (u16)(u >> 16);
}
__device__ __forceinline__ float bf2f(u16 b) {
    return __uint_as_float((u32)b << 16);
}

__device__ __forceinline__ void gload16(const u16* g, u16* l) {
    __builtin_amdgcn_global_load_lds(
        (const __attribute__((address_space(1))) void*)g,
        (__attribute__((address_space(3))) void*)l,
        16, 0, 0);
}

#define WAITV(N) asm volatile("s_waitcnt vmcnt(" #N ")" ::: "memory")
#define SCHEDB() __builtin_amdgcn_sched_barrier(0)
#define BAR()    __builtin_amdgcn_s_barrier()

// ----------------------------------------------------- fused converts -------
__global__ __launch_bounds__(256)
void cvt_all(const float* __restrict__ X, u16* __restrict__ Xb,
             const float* __restrict__ w0, const float* __restrict__ w1,
             const float* __restrict__ w2, const float* __restrict__ w3,
             const float* __restrict__ w4, u16* __restrict__ wt) {
    const int bx  = blockIdx.x;
    const int tid = threadIdx.x;
    if (bx < 4096) {
        const long i = (long)(bx * 256 + tid) * 8;
        float4 a = *(const float4*)(X + i);
        float4 b = *(const float4*)(X + i + 4);
        u16x8 r;
        r[0] = f2bf(a.x); r[1] = f2bf(a.y); r[2] = f2bf(a.z); r[3] = f2bf(a.w);
        r[4] = f2bf(b.x); r[5] = f2bf(b.y); r[6] = f2bf(b.z); r[7] = f2bf(b.w);
        *(u16x8*)(Xb + i) = r;
        return;
    }
    const int wb  = bx - 4096;
    const int wz  = wb >> 10;
    const int rem = wb & 1023;
    const float* srcs[5] = {w0, w1, w2, w3, w4};
    const float* W = srcs[wz];
    u16* WT = wt + (long)wz * 1048576;
    __shared__ float t[32][33];
    const int tx = tid & 31, ty = tid >> 5;
    const int n0 = (rem & 31) * 32, k0 = (rem >> 5) * 32;
    #pragma unroll
    for (int r = 0; r < 4; ++r)
        t[ty + 8 * r][tx] = W[(long)(k0 + ty + 8 * r) * 1024 + n0 + tx];
    __syncthreads();
    #pragma unroll
    for (int r = 0; r < 4; ++r)
        WT[(long)(n0 + ty + 8 * r) * 1024 + k0 + tx] = f2bf(t[tx][ty + 8 * r]);
}

enum { EPI_QKV = 0, EPI_SCORES = 1, EPI_ADDX_BF16 = 3,
       EPI_BIAS_RELU_BF16 = 4, EPI_BIAS_ADDX_F32 = 5 };

// -------------------------------------- GEMM 256x128, BK=32, 2 blocks/CU ----
// R13-proven (QKV 61.3us, MfmaUtil 35%, conflicts 0, 52 VGPR no spill).
#define BM3 256
#define BN3 128
#define BK3 32
#define S3_A (BM3 * BK3)
#define S3_B (BN3 * BK3)
#define S3SZ (S3_A + S3_B)

template <int EPI>
__global__ __launch_bounds__(512, 2)
void gemm_bt32(const u16* __restrict__ A, const u16* __restrict__ Bt,
               void* __restrict__ Cout, void* __restrict__ CoutK,
               void* __restrict__ CoutV,
               const int M, const int N, const int K,
               const long sA, const long sB,
               const float scale) {
    const int GX = gridDim.x, GY = gridDim.y;
    const int p  = blockIdx.x + GX * (blockIdx.y + GY * blockIdx.z);
    const int slab = (p & 7) + 8 * (p / (8 * GY));
    const int vy   = (p >> 3) % GY;
    const int vx   = slab % GX;
    const int bz   = slab / GX;

    const u16* Ab = A + (long)bz * sA;
    const u16* Bb = Bt + (long)bz * sB;

    const int tid  = threadIdx.x;
    const int lane = tid & 63;
    const int w    = tid >> 6;
    const int wrg  = (w >> 1) * 64;
    const int wcg  = (w & 1) * 64;
    const int m0   = vx * BM3;
    const int n0   = vy * BN3;

    __shared__ __align__(16) u16 LDS[3 * S3SZ];   // 72 KiB

    f32x4 acc[4][4] = {};

    const long Kl = K;
    const int schunk = ((lane & 3) ^ ((lane >> 3) & 3)) * 8;
    const u16* Ag = Ab + (long)(m0 + w * 32 + (lane >> 2)) * Kl + schunk;
    const u16* Bg = Bb + (long)(n0 + w * 16 + (lane >> 2)) * Kl + schunk;

    const int rbase = lane & 15;
    const int koff  = ((lane >> 4) ^ ((rbase >> 1) & 3)) * 8;

    const int dAoff = (w * 32) * BK3;
    const int dBoff = S3_A + (w * 16) * BK3;

    #define LDA3(mi) (*(const bf16x8*)(Asl + (wrg + (mi) * 16 + rbase) * BK3 + koff))
    #define LDB3(ni) (*(const bf16x8*)(Bsl + (wcg + (ni) * 16 + rbase) * BK3 + koff))
    #define STAGE3(KT, SLOT) do {                                  \
        u16* a_ = &LDS[(SLOT) * S3SZ + dAoff];                     \
        u16* b_ = &LDS[(SLOT) * S3SZ + dBoff];                     \
        gload16(Ag + (KT), a_);                                    \
        gload16(Ag + (KT) + 16 * Kl, a_ + 16 * BK3);               \
        gload16(Bg + (KT), b_);                                    \
    } while (0)

    const int nt = K / BK3;
    STAGE3(0, 0);
    STAGE3(BK3, 1);
    WAITV(3);
    BAR();

    int s = 0;
    for (int t = 0; t < nt; ++t) {
        const u16* Asl = &LDS[s * S3SZ];
        const u16* Bsl = &LDS[s * S3SZ + S3_A];
        const int s2 = (s + 2 >= 3) ? s - 1 : s + 2;
        const bool st = (t + 2 < nt);

        if (st) STAGE3((long)(t + 2) * BK3, s2);

        bf16x8 af[4], bf[4];
        #pragma unroll
        for (int mi = 0; mi < 4; ++mi) af[mi] = LDA3(mi);
        #pragma unroll
        for (int ni = 0; ni < 4; ++ni) bf[ni] = LDB3(ni);
        #pragma unroll
        for (int mi = 0; mi < 4; ++mi)
            #pragma unroll
            for (int ni = 0; ni < 4; ++ni)
                acc[mi][ni] = __builtin_amdgcn_mfma_f32_16x16x32_bf16(
                    af[mi], bf[ni], acc[mi][ni], 0, 0, 0);

        SCHEDB();
        if (st) { WAITV(3); } else { WAITV(0); }
        BAR();
        SCHEDB();
        s = (s == 2) ? 0 : s + 1;
    }
    #undef LDA3
    #undef LDB3
    #undef STAGE3

    const int colb = wcg + (lane & 15);
    const int rq   = (lane >> 4) * 4;
    #pragma unroll
    for (int mi = 0; mi < 4; ++mi) {
        #pragma unroll
        for (int ni = 0; ni < 4; ++ni) {
            f32x4 v = acc[mi][ni];
            const int gr0 = m0 + wrg + mi * 16 + rq;
            const int gc  = n0 + colb + ni * 16;
            if constexpr (EPI == EPI_QKV) {
                if (bz == 2) {
                    u16x4 p2;
                    p2[0] = f2bf(v[0]); p2[1] = f2bf(v[1]);
                    p2[2] = f2bf(v[2]); p2[3] = f2bf(v[3]);
                    u16* C = (u16*)CoutV;
                    const long off = ((long)(gr0 >> 11)) * 2097152 +
                                     (long)gc * 2048 + (gr0 & 2047);
                    *(u16x4*)(C + off) = p2;
                } else {
                    u16* C = (u16*)(bz == 0 ? Cout : CoutK);
                    #pragma unroll
                    for (int j = 0; j < 4; ++j)
                        C[(long)(gr0 + j) * N + gc] = f2bf(v[j]);
                }
            } else if constexpr (EPI == EPI_SCORES) {
                u16* Sb = (u16*)(bz < 2 ? Cout : CoutK) + (long)(bz & 1) * 4194304;
                #pragma unroll
                for (int j = 0; j < 4; ++j)
                    Sb[(long)(gr0 + j) * N + gc] = f2bf(v[j] * scale);
            }
        }
    }
}

// ------------------------------------------------- GEMM small (256x128, R10) -
// A2: second A base for split-P (PV reads P from Qb [b0-1] / outHi [b2-3]).
// Base = (bz<2 ? A : A2) + (bz&1)*sA. Residual Xres is bf16 (Xb).
#define BML 256
#define BNL 128
#define BKW 64
#define LSLOT_A (BML * BKW)
#define LSLOT_B (BNL * BKW)
#define LSLOTSZ (LSLOT_A + LSLOT_B)

template <int EPI>
__global__ __launch_bounds__(512, 1)
void gemm_bt(const u16* __restrict__ A, const u16* __restrict__ A2,
             const u16* __restrict__ Bt,
             void* __restrict__ Cout,
             const float* __restrict__ bias, const u16* __restrict__ Xres,
             const int M, const int N, const int K,
             const long sA, const long sB, const long sC, const long sX,
             const float scale) {
    const int GX = gridDim.x, GY = gridDim.y;
    const int p  = blockIdx.x + GX * (blockIdx.y + GY * blockIdx.z);
    const int slab = (p & 7) + 8 * (p / (8 * GY));
    const int vy   = (p >> 3) % GY;
    const int vx   = slab % GX;
    const int bz   = slab / GX;

    const u16* Ab = (bz < 2 ? A : A2) + (long)(bz & 1) * sA;
    const u16* Bb = Bt + (long)bz * sB;
    const u16* Xr = Xres ? Xres + (long)bz * sX : nullptr;

    const int tid  = threadIdx.x;
    const int lane = tid & 63;
    const int w    = tid >> 6;
    const int wrg  = (w >> 1) * 64;
    const int wcg  = (w & 1) * 64;
    const int m0   = vx * BML;
    const int n0   = vy * BNL;

    __shared__ __align__(16) u16 LDS[3 * LSLOTSZ];   // 144 KiB

    f32x4 acc[4][4] = {};

    const long Kl = K;
    const int schunk = ((lane & 7) ^ (lane >> 3)) * 8;
    const u16* Ag = Ab + (long)(m0 + w * 32 + (lane >> 3)) * Kl + schunk;
    const u16* Bg = Bb + (long)(n0 + w * 16 + (lane >> 3)) * Kl + schunk;

    const int rbase = lane & 15;
    const int rx    = rbase & 7;
    const int q4    = lane >> 4;

    const int dAoff = (w * 32) * BKW;
    const int dBoff = LSLOT_A + (w * 16) * BKW;

    #define LDAL(mi, ks) (*(const bf16x8*)(Asl + (wrg + (mi) * 16 + rbase) * BKW \
                         + ((((ks) * 4 + q4) ^ rx)) * 8))
    #define LDBL(ni, ks) (*(const bf16x8*)(Bsl + (wcg + (ni) * 16 + rbase) * BKW \
                         + ((((ks) * 4 + q4) ^ rx)) * 8))

    const int nt = K / BKW;
    {
        u16* d0 = &LDS[0];
        gload16(Ag, d0 + dAoff);
        gload16(Ag + 8 * Kl,  d0 + dAoff + 512);
        gload16(Ag + 16 * Kl, d0 + dAoff + 1024);
        gload16(Ag + 24 * Kl, d0 + dAoff + 1536);
        gload16(Bg, d0 + dBoff);
        gload16(Bg + 8 * Kl,  d0 + dBoff + 512);
        u16* d1 = &LDS[LSLOTSZ];
        gload16(Ag + BKW, d1 + dAoff);
        gload16(Ag + BKW + 8 * Kl,  d1 + dAoff + 512);
        gload16(Ag + BKW + 16 * Kl, d1 + dAoff + 1024);
        gload16(Ag + BKW + 24 * Kl, d1 + dAoff + 1536);
        gload16(Bg + BKW, d1 + dBoff);
        gload16(Bg + BKW + 8 * Kl,  d1 + dBoff + 512);
    }
    WAITV(6);
    BAR();

    int s = 0;
    for (int t = 0; t < nt; ++t) {
        const u16* Asl = &LDS[s * LSLOTSZ];
        const u16* Bsl = &LDS[s * LSLOTSZ + LSLOT_A];
        const int s2 = (s + 2 >= 3) ? s - 1 : s + 2;
        u16* dA = &LDS[s2 * LSLOTSZ] + dAoff;
        u16* dB = &LDS[s2 * LSLOTSZ] + dBoff;
        const bool st = (t + 2 < nt);
        const long kt2 = (long)(t + 2) * BKW;

        if (st) {
            gload16(Ag + kt2, dA);
            gload16(Ag + kt2 + 8 * Kl,  dA + 512);
            gload16(Ag + kt2 + 16 * Kl, dA + 1024);
            gload16(Ag + kt2 + 24 * Kl, dA + 1536);
            gload16(Bg + kt2, dB);
            gload16(Bg + kt2 + 8 * Kl,  dB + 512);
        }

        bf16x8 af[4][2], bf[4][2];
        #pragma unroll
        for (int mi = 0; mi < 4; ++mi) {
            af[mi][0] = LDAL(mi, 0);
            af[mi][1] = LDAL(mi, 1);
        }
        #pragma unroll
        for (int ni = 0; ni < 4; ++ni) {
            bf[ni][0] = LDBL(ni, 0);
            bf[ni][1] = LDBL(ni, 1);
        }
        #pragma unroll
        for (int ks = 0; ks < 2; ++ks)
            #pragma unroll
            for (int mi = 0; mi < 4; ++mi)
                #pragma unroll
                for (int ni = 0; ni < 4; ++ni)
                    acc[mi][ni] = __builtin_amdgcn_mfma_f32_16x16x32_bf16(
                        af[mi][ks], bf[ni][ks], acc[mi][ni], 0, 0, 0);

        SCHEDB();
        if (st) { WAITV(6); } else { WAITV(0); }
        BAR();
        SCHEDB();
        s = (s == 2) ? 0 : s + 1;
    }
    #undef LDAL
    #undef LDBL

    const int colb = wcg + (lane & 15);
    const int rq   = (lane >> 4) * 4;
    #pragma unroll
    for (int mi = 0; mi < 4; ++mi) {
        #pragma unroll
        for (int ni = 0; ni < 4; ++ni) {
            f32x4 v = acc[mi][ni];
            const int gr0 = m0 + wrg + mi * 16 + rq;
            const int gc  = n0 + colb + ni * 16;
            #pragma unroll
            for (int j = 0; j < 4; ++j) {
                const long idx = (long)(gr0 + j) * N + gc;
                float val = v[j];
                if constexpr (EPI == EPI_ADDX_BF16) {
                    val += bf2f(Xr[idx]);
                    ((u16*)Cout + (long)bz * sC)[idx] = f2bf(val);
                } else if constexpr (EPI == EPI_BIAS_RELU_BF16) {
                    val = fmaxf(val + bias[gc], 0.0f);
                    ((u16*)Cout + (long)bz * sC)[idx] = f2bf(val);
                } else if constexpr (EPI == EPI_BIAS_ADDX_F32) {
                    ((float*)Cout + (long)bz * sC)[idx] =
                        val + bias[gc] + bf2f(Xr[idx]);
                }
            }
        }
    }
}

// ---------------------------------------------------------------- softmax ---
// reads bf16 raw scores (SbLo = out-region low / SbHi = H1b); writes fp32
// attn + bf16 P split (P-lo -> Qb, P-hi -> out-region high). outLo reads and
// outHi writes are disjoint halves of the out region.
__global__ __launch_bounds__(256)
void softmax_rows(const u16* __restrict__ SbLo, const u16* __restrict__ SbHi,
                  float* __restrict__ attn,
                  u16* __restrict__ Plo, u16* __restrict__ Phi) {
    const int row  = blockIdx.x;
    const u16* srow = (row < 4096 ? SbLo + (long)row * 2048
                                  : SbHi + (long)(row - 4096) * 2048);
    const int tid  = threadIdx.x;
    const int lane = tid & 63;
    const int w    = tid >> 6;

    u16x8 raw = *(const u16x8*)(srow + tid * 8);
    float v[8];
    #pragma unroll
    for (int i = 0; i < 8; ++i) v[i] = bf2f(raw[i]);

    float m = fmaxf(fmaxf(fmaxf(v[0], v[1]), fmaxf(v[2], v[3])),
                    fmaxf(fmaxf(v[4], v[5]), fmaxf(v[6], v[7])));
    #pragma unroll
    for (int o = 32; o > 0; o >>= 1) m = fmaxf(m, __shfl_xor(m, o));
    __shared__ float redm[4];
    if (lane == 0) redm[w] = m;
    __syncthreads();
    m = fmaxf(fmaxf(redm[0], redm[1]), fmaxf(redm[2], redm[3]));

    float e[8];
    #pragma unroll
    for (int i = 0; i < 8; ++i) e[i] = __expf(v[i] - m);
    float s = ((e[0] + e[1]) + (e[2] + e[3])) + ((e[4] + e[5]) + (e[6] + e[7]));
    #pragma unroll
    for (int o = 32; o > 0; o >>= 1) s += __shfl_xor(s, o);
    __shared__ float reds[4];
    if (lane == 0) reds[w] = s;
    __syncthreads();
    s = (reds[0] + reds[1]) + (reds[2] + reds[3]);
    const float inv = 1.0f / s;

    float4 o0, o1;
    o0.x = e[0] * inv; o0.y = e[1] * inv; o0.z = e[2] * inv; o0.w = e[3] * inv;
    o1.x = e[4] * inv; o1.y = e[5] * inv; o1.z = e[6] * inv; o1.w = e[7] * inv;
    float* ap = attn + (long)row * 2048 + tid * 8;
    *(float4*)(ap)     = o0;
    *(float4*)(ap + 4) = o1;

    u16x8 pb;
    pb[0] = f2bf(o0.x); pb[1] = f2bf(o0.y); pb[2] = f2bf(o0.z); pb[3] = f2bf(o0.w);
    pb[4] = f2bf(o1.x); pb[5] = f2bf(o1.y); pb[6] = f2bf(o1.z); pb[7] = f2bf(o1.w);
    u16* prow = (row < 4096 ? Plo + (long)row * 2048
                            : Phi + (long)(row - 4096) * 2048);
    *(u16x8*)(prow + tid * 8) = pb;
}

// ------------------------------------------------------------------ launch --
extern "C" void kernel_launch(void* const* d_in, const int* in_sizes, int n_in,
                              void* d_out, int out_size, void* d_ws, size_t ws_size,
                              hipStream_t stream) {
    const float* X  = (const float*)d_in[0];
    const float* Wq = (const float*)d_in[1];
    const float* Wk = (const float*)d_in[2];
    const float* Wv = (const float*)d_in[3];
    const float* W1 = (const float*)d_in[4];
    const float* b1 = (const float*)d_in[5];
    const float* W2 = (const float*)d_in[6];
    const float* b2 = (const float*)d_in[7];

    float* out  = (float*)d_out;                    // [4,2048,1024]
    float* attn = out + (size_t)8388608;            // [4,2048,2048]

    char* ws = (char*)d_ws;
    u16* Xb  = (u16*)(ws);                               // 16 MiB, ALIVE to W2
    u16* Qb  = (u16*)(ws + (size_t)16 * 1024 * 1024);    // Q -> P-lo
    u16* Kb  = (u16*)(ws + (size_t)32 * 1024 * 1024);    // K -> Hb
    u16* VT  = (u16*)(ws + (size_t)48 * 1024 * 1024);    // V^T [b][d][s]
    u16* H1b = (u16*)(ws + (size_t)64 * 1024 * 1024);    // SbHi -> H1
    u16* WTs = (u16*)(ws + (size_t)80 * 1024 * 1024);    // 10 MiB
    u16* W1T = WTs + (size_t)3 * 1048576;
    u16* W2T = WTs + (size_t)4 * 1048576;
    // out region (33.5 MB fp32, rewritten by W2): low half = SbLo (scores
    // b0-1, bf16), high half = P-hi (b2-3, bf16).
    u16* SbLo = (u16*)out;                               // 16.78 MB
    u16* Phi  = (u16*)(out + (size_t)4194304);           // 16.78 MB
    u16* SbHi = H1b;
    u16* Plo  = Qb;
    u16* Hb   = Kb;

    cvt_all<<<9216, 256, 0, stream>>>(X, Xb, Wq, Wk, Wv, W1, W2, WTs);

    // fused Q,K,V
    gemm_bt32<EPI_QKV><<<dim3(32, 8, 3), 512, 0, stream>>>(
        Xb, WTs, Qb, Kb, VT, 8192, 1024, 1024, 0, 1048576, 1.0f);

    // scores = Q @ K^T / 32 -> bf16 raw Sb (outLo / H1b)
    gemm_bt32<EPI_SCORES><<<dim3(8, 16, 4), 512, 0, stream>>>(
        Qb, Kb, SbLo, SbHi, nullptr, 2048, 2048, 1024,
        2048L * 1024, 2048L * 1024, 0.03125f);

    // softmax: Sb -> fp32 attn + bf16 P (Plo=Qb, Phi=outHi)
    softmax_rows<<<8192, 256, 0, stream>>>(SbLo, SbHi, attn, Plo, Phi);

    // attn_out = P @ V + X(bf16) -> Hb
    gemm_bt<EPI_ADDX_BF16><<<dim3(8, 8, 4), 512, 0, stream>>>(
        Plo, Phi, VT, Hb, nullptr, Xb, 2048, 1024, 2048,
        2048L * 2048, 1024L * 2048, 2048L * 1024, 2048L * 1024, 1.0f);

    // h1 = relu(Hb @ W1 + b1)
    gemm_bt<EPI_BIAS_RELU_BF16><<<dim3(32, 8, 1), 512, 0, stream>>>(
        Hb, Hb, W1T, H1b, b1, nullptr, 8192, 1024, 1024,
        0, 0, 0, 0, 1.0f);

    // out = h1 @ W2 + b2 + X(bf16)
    gemm_bt<EPI_BIAS_ADDX_F32><<<dim3(32, 8, 1), 512, 0, stream>>>(
        H1b, H1b, W2T, out, b2, Xb, 8192, 1024, 1024,
        0, 0, 0, 0, 1.0f);
}